// Round 12
// baseline (194.919 us; speedup 1.0000x reference)
//
#include <hip/hip_runtime.h>
#include <stdint.h>

#define D_DIM 128
#define NROW 8192          // 2B
#define L2EPS 1e-12f
#define SCALE_A 14.426950408889634f  // 10/ln2: MFMA out = sim*10/ln2 = exp2 arg
#define LN2 0.6931471805599453f
#define NPART 50           // row slots 0..16 (mb), col slots 17..48, diag col 49
#define NBLK 1088          // 17 * 64

typedef __attribute__((ext_vector_type(4))) int   i32x4;
typedef __attribute__((ext_vector_type(8))) int   i32x8;
typedef __attribute__((ext_vector_type(4))) float f32x4;

static __device__ inline i32x8 cat8(i32x4 lo, i32x4 hi) {
    i32x8 r;
    r[0] = lo[0]; r[1] = lo[1]; r[2] = lo[2]; r[3] = lo[3];
    r[4] = hi[0]; r[5] = hi[1]; r[6] = hi[2]; r[7] = hi[3];
    return r;
}

// Pack 16 fp32 (scaled) -> 16 fp8 e4m3 bytes in global element order.
static __device__ inline i32x4 pack16(const float* e, float sc) {
    i32x4 u;
#pragma unroll
    for (int d = 0; d < 4; d++) {
        int w = __builtin_amdgcn_cvt_pk_fp8_f32(e[4 * d] * sc, e[4 * d + 1] * sc, 0, false);
        w = __builtin_amdgcn_cvt_pk_fp8_f32(e[4 * d + 2] * sc, e[4 * d + 3] * sc, w, true);
        u[d] = w;
    }
    return u;
}

// Load 32 fp32 of row `grow`, bytes [quad*128,+128); return sum of squares
// of the FULL row via quad-reduce (shfl over lane bits 4,5).
static __device__ inline float load_row32(const float* __restrict__ xi,
                                          const float* __restrict__ xj,
                                          int grow, int quad, float* e) {
    const float* src = (grow < 4096) ? (xi + (size_t)grow * D_DIM)
                                     : (xj + (size_t)(grow - 4096) * D_DIM);
    const float* sq = src + quad * 32;
    float ss = 0.f;
#pragma unroll
    for (int k2 = 0; k2 < 8; k2++) {
        float4 v = *(const float4*)(sq + k2 * 4);
        e[k2 * 4 + 0] = v.x; e[k2 * 4 + 1] = v.y;
        e[k2 * 4 + 2] = v.z; e[k2 * 4 + 3] = v.w;
        ss += v.x * v.x + v.y * v.y + v.z * v.z + v.w * v.w;
    }
    ss += __shfl_xor(ss, 16, 64);
    ss += __shfl_xor(ss, 32, 64);
    return ss;
}

// Single fused kernel. Block (mb=bid>>6 in 0..16, rb=bid&63):
//  - normalizes its OWN bands from fp32 inputs (A band rb -> scaled fp8 frags
//    in registers; B bands c1/c2 -> fp8 into XOR-swizzled LDS). No global
//    fp8 arrays, no inter-block dependencies; ~50x duplicated normalize work
//    is ~200 MB of L2-resident fp32 reads (~6 us chip) -- cheaper than two
//    extra dispatches.
//  - r11's paired-circulant symmetric GEMM: mb<15 full credit; mb==15 second
//    band = distance-32 (e*=0.5, sub-diag = positives); mb==16 diag tile
//    (strictly upper). Every exp credits denom[row] (slot mb) and denom[col]
//    (slots 17+2mb/+1, diag 49). 50 single-writer slots.
//  - logsum fold: release-fence + done-counter; blocks 0..31 spin until all
//    NBLK done, then each reduces 256 rows; last of the 32 combines -> out.
__global__ __launch_bounds__(256) void k_all(
        const float* __restrict__ xi, const float* __restrict__ xj,
        float* __restrict__ part, float* __restrict__ pos_part,
        float* __restrict__ ls_part, unsigned* __restrict__ done,
        float* __restrict__ out) {
    __shared__ __align__(16) uint8_t lds[32768];   // 256 B-rows x 128 B fp8

    const int t = threadIdx.x;
    const int wave = t >> 6, lane = t & 63;
    const int quad = lane >> 4, lc = lane & 15;

    const int mb = blockIdx.x >> 6;     // 0..16
    const int rb = blockIdx.x & 63;
    const int rowbase = rb * 128;
    const bool diag = (mb == 16);
    const int c1 = diag ? rb : (rb + 2 * mb + 1) & 63;
    const int c2 = (rb + 2 * mb + 2) & 63;          // unused when diag

    // ---- Build B tile in LDS (normalize fp32 -> fp8, swizzled) ----
    // Local row rl: band c1 rows 0..127, band c2 rows 128..255.
    // Lane holds elems [quad*32,+32) = 16B-units 2q,2q+1; unit u of row r
    // goes to LDS slot-unit u^(r&7); r&7 == lc&7 for our row assignment.
    {
        const int nrr = diag ? 2 : 4;   // rows-per-wave = nrr*16
        for (int rr = 0; rr < nrr; rr++) {
            const int rl = wave * (nrr * 16) + rr * 16 + lc;
            const int band = (rl < 128) ? c1 : c2;
            const int grow = band * 128 + (rl & 127);
            float e[32];
            const float ss = load_row32(xi, xj, grow, quad, e);
            const float sc = 1.0f / fmaxf(sqrtf(ss), L2EPS);
            const i32x4 u0 = pack16(e, sc);
            const i32x4 u1 = pack16(e + 16, sc);
            const int m7 = lc & 7;
            *(i32x4*)&lds[rl * D_DIM + (((2 * quad)     ^ m7) * 16)] = u0;
            *(i32x4*)&lds[rl * D_DIM + (((2 * quad + 1) ^ m7) * 16)] = u1;
        }
    }

    // ---- A fragments in registers (normalize + scale by 10/ln2) ----
    i32x8 afr[2];
#pragma unroll
    for (int i = 0; i < 2; i++) {
        const int grow = rowbase + wave * 32 + i * 16 + lc;
        float e[32];
        const float ss = load_row32(xi, xj, grow, quad, e);
        const float sc = SCALE_A / fmaxf(sqrtf(ss), L2EPS);
        afr[i] = cat8(pack16(e, sc), pack16(e + 16, sc));
    }

    __syncthreads();   // B tile resident; j-loops below are barrier-free

    float rs[2][4] = {{0.f,0.f,0.f,0.f},{0.f,0.f,0.f,0.f}};
    float cs[16];
#pragma unroll
    for (int j = 0; j < 16; j++) cs[j] = 0.f;
    float posp = 0.f;
    const int rl0 = wave * 32 + quad * 4;   // local row = rl0 + i*16 + r

#define MFMA_J(j, A0, A1)                                                     \
    i32x4 blo, bhi; {                                                         \
        const int rowb = ((j) * 16 + lc) * D_DIM;                             \
        blo = *(const i32x4*)&lds[rowb + (((quad * 2)     ^ (lc & 7)) * 16)]; \
        bhi = *(const i32x4*)&lds[rowb + (((quad * 2 + 1) ^ (lc & 7)) * 16)]; \
    }                                                                         \
    const i32x8 bfr = cat8(blo, bhi);                                         \
    f32x4 z4 = {0.f, 0.f, 0.f, 0.f};                                          \
    f32x4 A0 = __builtin_amdgcn_mfma_scale_f32_16x16x128_f8f6f4(              \
                   afr[0], bfr, z4, 0, 0, 0, 127, 0, 127);                    \
    f32x4 A1 = __builtin_amdgcn_mfma_scale_f32_16x16x128_f8f6f4(              \
                   afr[1], bfr, z4, 0, 0, 0, 127, 0, 127);

    if (!diag) {
#pragma unroll
        for (int j = 0; j < 8; j++) {        // band c1: always full credit
            MFMA_J(j, a0, a1)
#pragma unroll
            for (int r = 0; r < 4; r++) {
                const float e0 = exp2f(a0[r]);
                const float e1 = exp2f(a1[r]);
                rs[0][r] += e0;
                rs[1][r] += e1;
                cs[j] += e0 + e1;
            }
        }
        if (mb < 15) {                        // band c2: full credit
#pragma unroll
            for (int j = 8; j < 16; j++) {
                MFMA_J(j, a0, a1)
#pragma unroll
                for (int r = 0; r < 4; r++) {
                    const float e0 = exp2f(a0[r]);
                    const float e1 = exp2f(a1[r]);
                    rs[0][r] += e0;
                    rs[1][r] += e1;
                    cs[j] += e0 + e1;
                }
            }
        } else {                              // distance-32: halve; diag = positives
#pragma unroll
            for (int j = 8; j < 16; j++) {
                MFMA_J(j, a0, a1)
                const int clb = (j - 8) * 16 + lc;   // band-local col
#pragma unroll
                for (int i = 0; i < 2; i++)
#pragma unroll
                    for (int r = 0; r < 4; r++) {
                        const float s = (i ? a1 : a0)[r];
                        const float e = 0.5f * exp2f(s);
                        if (clb == rl0 + i * 16 + r) posp += s;
                        rs[i][r] += e;
                        cs[j] += e;
                    }
            }
        }
    } else {                                  // diagonal tile: strictly upper
#pragma unroll
        for (int j = 0; j < 8; j++) {
            MFMA_J(j, a0, a1)
            const int cl = j * 16 + lc;
#pragma unroll
            for (int i = 0; i < 2; i++)
#pragma unroll
                for (int r = 0; r < 4; r++) {
                    const float s = (i ? a1 : a0)[r];
                    const float e = (cl > rl0 + i * 16 + r) ? exp2f(s) : 0.f;
                    rs[i][r] += e;
                    cs[j] += e;
                }
        }
    }
#undef MFMA_J

    // Row credits -> slot mb (reduce over the 16 col-lanes).
#pragma unroll
    for (int i = 0; i < 2; i++)
#pragma unroll
        for (int r = 0; r < 4; r++) {
            float v = rs[i][r];
            v += __shfl_xor(v, 1, 64);
            v += __shfl_xor(v, 2, 64);
            v += __shfl_xor(v, 4, 64);
            v += __shfl_xor(v, 8, 64);
            if (lc == 0)
                part[(size_t)mb * NROW + rowbase + rl0 + i * 16 + r] = v;
        }

    // Col credits: quad-reduce, cross-wave LDS reduce, one store per col.
#pragma unroll
    for (int j = 0; j < 16; j++) {
        cs[j] += __shfl_xor(cs[j], 16, 64);
        cs[j] += __shfl_xor(cs[j], 32, 64);
    }
    __syncthreads();                    // all B reads done; reuse LDS
    float* colred = (float*)lds;        // [4][256] + posw at [1024..]
    if (quad == 0) {
#pragma unroll
        for (int j = 0; j < 16; j++)
            colred[wave * 256 + j * 16 + lc] = cs[j];
    }
    if (mb == 15) {
#pragma unroll
        for (int mm = 32; mm >= 1; mm >>= 1) posp += __shfl_xor(posp, mm, 64);
        if (lane == 0) colred[1024 + wave] = posp;
    }
    __syncthreads();
    if (t < 256) {
        const float v = colred[t] + colred[256 + t] + colred[512 + t] + colred[768 + t];
        if (!diag) {
            const int slot = 17 + 2 * mb + (t >> 7);
            const int band = (t < 128) ? c1 : c2;
            part[(size_t)slot * NROW + band * 128 + (t & 127)] = v;
        } else if (t < 128) {
            part[(size_t)49 * NROW + c1 * 128 + t] = v;
        }
    }
    if (mb == 15 && t == 0)
        pos_part[rb] = colred[1024] + colred[1025] + colred[1026] + colred[1027];

    // ---- Fused logsum: release, count, blocks 0..31 finish the job ----
    __threadfence();
    if (t == 0) atomicAdd(&done[0], 1u);

    if (blockIdx.x < 32) {
        if (t == 0) {
            while (__hip_atomic_load(&done[0], __ATOMIC_ACQUIRE,
                                     __HIP_MEMORY_SCOPE_AGENT) < (unsigned)NBLK)
                __builtin_amdgcn_s_sleep(2);
        }
        __syncthreads();
        __threadfence();
        const int row = blockIdx.x * 256 + t;
        float d = 0.f;
#pragma unroll
        for (int p = 0; p < NPART; p++) d += part[(size_t)p * NROW + row];
        float v = __logf(d);
#pragma unroll
        for (int m = 32; m >= 1; m >>= 1) v += __shfl_xor(v, m, 64);
        __syncthreads();                // lds free again
        if ((t & 63) == 0) ((float*)lds)[t >> 6] = v;
        __syncthreads();
        if (t == 0) {
            float* f = (float*)lds;
            ls_part[blockIdx.x] = f[0] + f[1] + f[2] + f[3];
            __threadfence();
            const unsigned prev = atomicAdd(&done[1], 1u);
            if (prev == 31u) {          // last logsum block: combine
                __threadfence();
                float L = 0.f;
#pragma unroll
                for (int b = 0; b < 32; b++) L += ls_part[b];
                float P = 0.f;
#pragma unroll
                for (int b = 0; b < 64; b++) P += pos_part[b];
                out[0] = (L - P * LN2) / (float)NROW;
            }
        }
    }
}

extern "C" void kernel_launch(void* const* d_in, const int* in_sizes, int n_in,
                              void* d_out, int out_size, void* d_ws, size_t ws_size,
                              hipStream_t stream) {
    const float* xi = (const float*)d_in[0];
    const float* xj = (const float*)d_in[1];
    float* part = (float*)d_ws;                       // 50 x 8192 f32 = 1.6 MB
    float* pos_part = part + (size_t)NPART * NROW;    // 64 f32 (single-writer)
    float* ls_part = pos_part + 64;                   // 32 f32 (single-writer)
    unsigned* done = (unsigned*)(ls_part + 32);       // 2 counters (need zero)
    float* out = (float*)d_out;

    hipMemsetAsync(done, 0, 2 * sizeof(unsigned), stream);
    hipLaunchKernelGGL(k_all, dim3(NBLK), dim3(256), 0, stream,
                       xi, xj, part, pos_part, ls_part, done, out);
}

// Round 13
// 84.175 us; speedup vs baseline: 2.3157x; 2.3157x over previous
//
#include <hip/hip_runtime.h>
#include <stdint.h>

#define D_DIM 128
#define NROW 8192          // 2B
#define L2EPS 1e-12f
// Want MFMA output = sim * 10/ln2 (the exp2 argument). Using MX scales
// A=2^4, B=2^0 and data pre-scaled by sqrt((10/ln2)/16):
#define SCALE_PRE 0.9495707f     // sqrt(14.426950408889634 / 16)
#define LN2 0.6931471805599453f
#define NPART 50           // row slots 0..16 (mb), col slots 17..48, diag col 49

typedef __attribute__((ext_vector_type(4))) int   i32x4;
typedef __attribute__((ext_vector_type(8))) int   i32x8;
typedef __attribute__((ext_vector_type(4))) float f32x4;

#define AS1 __attribute__((address_space(1)))
#define AS3 __attribute__((address_space(3)))

static __device__ inline void gload_lds16(const void* g, void* l) {
    __builtin_amdgcn_global_load_lds((const AS1 uint32_t*)g, (AS3 uint32_t*)l, 16, 0, 0);
}

static __device__ inline i32x8 cat8(i32x4 lo, i32x4 hi) {
    i32x8 r;
    r[0] = lo[0]; r[1] = lo[1]; r[2] = lo[2]; r[3] = lo[3];
    r[4] = hi[0]; r[5] = hi[1]; r[6] = hi[2]; r[7] = hi[3];
    return r;
}

// K1: L2-normalize rows of [x_i; x_j]; emit ONE fp8 e4m3 array
// z8 = fp8(z * SCALE_PRE), shared by A and B operands (MX scales 2^4 / 2^0
// reconstruct the 10/ln2 factor in the MFMA output).
__global__ __launch_bounds__(256) void k_normalize(
        const float* __restrict__ xi, const float* __restrict__ xj,
        uint8_t* __restrict__ z8, float* __restrict__ pos_acc,
        float* __restrict__ logsum, unsigned* __restrict__ done_ct) {
    const int wave = threadIdx.x >> 6;
    const int lane = threadIdx.x & 63;
    const int row = blockIdx.x * 4 + wave;
    const float* src = (row < 4096) ? (xi + (size_t)row * D_DIM)
                                    : (xj + (size_t)(row - 4096) * D_DIM);
    float2 v = *(const float2*)(src + lane * 2);
    float ss = v.x * v.x + v.y * v.y;
#pragma unroll
    for (int m = 32; m >= 1; m >>= 1) ss += __shfl_xor(ss, m, 64);
    const float scale = SCALE_PRE / fmaxf(sqrtf(ss), L2EPS);
    const int pk = __builtin_amdgcn_cvt_pk_fp8_f32(v.x * scale, v.y * scale, 0, false);
    *(ushort*)(z8 + (size_t)row * D_DIM + lane * 2) = (ushort)pk;

    if (blockIdx.x == 0 && threadIdx.x == 0) {
        pos_acc[0] = 0.0f; logsum[0] = 0.0f; done_ct[0] = 0u;
    }
}

// K2 (paired-circulant symmetric): block (mb=bid>>6 in 0..16, rb=bid&63).
//  mb<16 : rows band rb x col bands c1=(rb+2mb+1)%64, c2=(rb+2mb+2)%64
//          (128x256 tile). Distances 1..31 covered once (full credit);
//          mb==15's second half = distance 32, double-enumerated -> e*=0.5,
//          sub-tile diagonal = positive pairs (both directions accumulated).
//  mb==16: diagonal tile rb x rb, strictly-upper (c>r) only.
// Each e credits denom[row] (slot mb) and denom[col] (slots 17+2mb / +1;
// diag col slot 49). All 50 slots single-writer & fully covered -> no atomics,
// no zeroing. B bands LDS-resident (XOR swizzle) after ONE barrier.
// MFMA: mfma_scale_f32_16x16x128_f8f6f4, scale_a=131 (x16), scale_b=127 (x1).
__global__ __launch_bounds__(256) void k_gemm(
        const uint8_t* __restrict__ z8, float* __restrict__ part,
        float* __restrict__ pos_acc) {
    __shared__ __align__(16) uint8_t lds[32768];   // 256 B-rows x 128 B fp8

    const int t = threadIdx.x;
    const int wave = t >> 6, lane = t & 63;
    const int quad = lane >> 4, lc = lane & 15;

    const int mb = blockIdx.x >> 6;     // 0..16
    const int rb = blockIdx.x & 63;
    const int rowbase = rb * 128;
    const bool diag = (mb == 16);
    const int c1 = diag ? rb : (rb + 2 * mb + 1) & 63;
    const int c2 = (rb + 2 * mb + 2) & 63;          // unused when diag

    // Stage B: band c1 -> lds rows 0..127, band c2 -> rows 128..255.
    // Slot s: row r=s>>3, slot-unit u holds global 16B-unit u^(r&7).
    {
        const uint8_t* zb1 = z8 + (size_t)c1 * 128 * D_DIM;
#pragma unroll
        for (int q = 0; q < 4; q++) {
            const int s = q * 256 + t;
            const int r = s >> 3;
            const int g = (s & 7) ^ (r & 7);
            gload_lds16(zb1 + (size_t)r * D_DIM + g * 16, &lds[s * 16]);
        }
        if (!diag) {
            const uint8_t* zb2 = z8 + (size_t)c2 * 128 * D_DIM;
#pragma unroll
            for (int q = 0; q < 4; q++) {
                const int s = q * 256 + t;
                const int r = s >> 3;
                const int g = (s & 7) ^ (r & 7);
                gload_lds16(zb2 + (size_t)r * D_DIM + g * 16, &lds[16384 + s * 16]);
            }
        }
    }

    // A fragments: 32 B of row (rowbase + wave*32 + i*16 + lc), bytes [quad*32,+32).
    i32x8 afr[2];
    {
        const uint8_t* pa = z8 + (size_t)(rowbase + wave * 32 + lc) * D_DIM + quad * 32;
#pragma unroll
        for (int i = 0; i < 2; i++) {
            i32x4 lo = *(const i32x4*)(pa + i * 16 * D_DIM);
            i32x4 hi = *(const i32x4*)(pa + i * 16 * D_DIM + 16);
            afr[i] = cat8(lo, hi);
        }
    }

    asm volatile("s_waitcnt vmcnt(0)" ::: "memory");
    __syncthreads();   // B resident; j-loops below are barrier-free

    float rs[2][4] = {{0.f,0.f,0.f,0.f},{0.f,0.f,0.f,0.f}};
    float cs[16];
#pragma unroll
    for (int j = 0; j < 16; j++) cs[j] = 0.f;
    float posp = 0.f;
    const int rl0 = wave * 32 + quad * 4;   // local row = rl0 + i*16 + r

    // B-row jr = j*16+lc; jr&7 == lc&7, so read slot-units (quad*2..+1)^(lc&7).
#define MFMA_J(j, A0, A1)                                                     \
    i32x4 blo, bhi; {                                                         \
        const int rowb = ((j) * 16 + lc) * D_DIM;                             \
        blo = *(const i32x4*)&lds[rowb + (((quad * 2)     ^ (lc & 7)) * 16)]; \
        bhi = *(const i32x4*)&lds[rowb + (((quad * 2 + 1) ^ (lc & 7)) * 16)]; \
    }                                                                         \
    const i32x8 bfr = cat8(blo, bhi);                                         \
    f32x4 z4 = {0.f, 0.f, 0.f, 0.f};                                          \
    f32x4 A0 = __builtin_amdgcn_mfma_scale_f32_16x16x128_f8f6f4(              \
                   afr[0], bfr, z4, 0, 0, 0, 131, 0, 127);                    \
    f32x4 A1 = __builtin_amdgcn_mfma_scale_f32_16x16x128_f8f6f4(              \
                   afr[1], bfr, z4, 0, 0, 0, 131, 0, 127);

    if (!diag) {
#pragma unroll
        for (int j = 0; j < 8; j++) {        // band c1: always full credit
            MFMA_J(j, a0, a1)
#pragma unroll
            for (int r = 0; r < 4; r++) {
                const float e0 = exp2f(a0[r]);
                const float e1 = exp2f(a1[r]);
                rs[0][r] += e0;
                rs[1][r] += e1;
                cs[j] += e0 + e1;
            }
        }
        if (mb < 15) {                        // band c2: full credit
#pragma unroll
            for (int j = 8; j < 16; j++) {
                MFMA_J(j, a0, a1)
#pragma unroll
                for (int r = 0; r < 4; r++) {
                    const float e0 = exp2f(a0[r]);
                    const float e1 = exp2f(a1[r]);
                    rs[0][r] += e0;
                    rs[1][r] += e1;
                    cs[j] += e0 + e1;
                }
            }
        } else {                              // distance-32: halve; diag = positives
#pragma unroll
            for (int j = 8; j < 16; j++) {
                MFMA_J(j, a0, a1)
                const int clb = (j - 8) * 16 + lc;   // band-local col
#pragma unroll
                for (int i = 0; i < 2; i++)
#pragma unroll
                    for (int r = 0; r < 4; r++) {
                        const float s = (i ? a1 : a0)[r];
                        const float e = 0.5f * exp2f(s);
                        if (clb == rl0 + i * 16 + r) posp += s;
                        rs[i][r] += e;
                        cs[j] += e;
                    }
            }
        }
    } else {                                  // diagonal tile: strictly upper
#pragma unroll
        for (int j = 0; j < 8; j++) {
            MFMA_J(j, a0, a1)
            const int cl = j * 16 + lc;
#pragma unroll
            for (int i = 0; i < 2; i++)
#pragma unroll
                for (int r = 0; r < 4; r++) {
                    const float s = (i ? a1 : a0)[r];
                    const float e = (cl > rl0 + i * 16 + r) ? exp2f(s) : 0.f;
                    rs[i][r] += e;
                    cs[j] += e;
                }
        }
    }
#undef MFMA_J

    // Row credits -> slot mb (reduce over the 16 col-lanes).
#pragma unroll
    for (int i = 0; i < 2; i++)
#pragma unroll
        for (int r = 0; r < 4; r++) {
            float v = rs[i][r];
            v += __shfl_xor(v, 1, 64);
            v += __shfl_xor(v, 2, 64);
            v += __shfl_xor(v, 4, 64);
            v += __shfl_xor(v, 8, 64);
            if (lc == 0)
                part[(size_t)mb * NROW + rowbase + rl0 + i * 16 + r] = v;
        }

    // Col credits: quad-reduce, cross-wave LDS reduce, one store per col.
#pragma unroll
    for (int j = 0; j < 16; j++) {
        cs[j] += __shfl_xor(cs[j], 16, 64);
        cs[j] += __shfl_xor(cs[j], 32, 64);
    }
    __syncthreads();                    // all B reads done; reuse LDS
    float* colred = (float*)lds;        // [4][256]
    if (quad == 0) {
#pragma unroll
        for (int j = 0; j < 16; j++)
            colred[wave * 256 + j * 16 + lc] = cs[j];
    }
    __syncthreads();
    if (t < 256) {
        const float v = colred[t] + colred[256 + t] + colred[512 + t] + colred[768 + t];
        if (!diag) {
            const int slot = 17 + 2 * mb + (t >> 7);
            const int band = (t < 128) ? c1 : c2;
            part[(size_t)slot * NROW + band * 128 + (t & 127)] = v;
        } else if (t < 128) {
            part[(size_t)49 * NROW + c1 * 128 + t] = v;
        }
    }

    if (mb == 15) {
#pragma unroll
        for (int mm = 32; mm >= 1; mm >>= 1) posp += __shfl_xor(posp, mm, 64);
        if (lane == 0) atomicAdd(pos_acc, posp);
    }
}

// K3 (fused logsum + combine): 32 blocks, one row per thread; last block
// (atomic counter) writes the final loss. pos_acc holds scaled sim over both
// appearances of each positive pair -> factor ln2.
__global__ __launch_bounds__(256) void k_logsum(
        const float* __restrict__ part, float* __restrict__ pos_acc,
        float* __restrict__ logsum, unsigned* __restrict__ done_ct,
        float* __restrict__ out) {
    const int row = blockIdx.x * 256 + threadIdx.x;
    float d = 0.f;
#pragma unroll
    for (int p = 0; p < NPART; p++) d += part[(size_t)p * NROW + row];
    float v = __logf(d);
#pragma unroll
    for (int m = 32; m >= 1; m >>= 1) v += __shfl_xor(v, m, 64);
    if ((threadIdx.x & 63) == 0) atomicAdd(logsum, v);
    __threadfence();
    __syncthreads();
    if (threadIdx.x == 0) {
        const unsigned prev = atomicAdd(done_ct, 1u);
        if (prev == gridDim.x - 1) {          // last block: all adds visible
            __threadfence();
            const float ls = atomicAdd(logsum, 0.0f);
            const float pp = atomicAdd(pos_acc, 0.0f);
            out[0] = (ls - pp * LN2) / (float)NROW;
        }
    }
}

extern "C" void kernel_launch(void* const* d_in, const int* in_sizes, int n_in,
                              void* d_out, int out_size, void* d_ws, size_t ws_size,
                              hipStream_t stream) {
    const float* xi = (const float*)d_in[0];
    const float* xj = (const float*)d_in[1];
    uint8_t* z8 = (uint8_t*)d_ws;                                // 1 MB fp8
    float* part = (float*)(z8 + (size_t)NROW * D_DIM);           // 50 x 8192 f32
    float* pos_acc = part + (size_t)NPART * NROW;
    float* logsum = pos_acc + 1;
    unsigned* done_ct = (unsigned*)(logsum + 1);
    float* out = (float*)d_out;

    hipLaunchKernelGGL(k_normalize, dim3(NROW / 4), dim3(256), 0, stream,
                       xi, xj, z8, pos_acc, logsum, done_ct);
    hipLaunchKernelGGL(k_gemm, dim3(17 * 64), dim3(256), 0, stream,
                       z8, part, pos_acc);
    hipLaunchKernelGGL(k_logsum, dim3(NROW / 256), dim3(256), 0, stream,
                       part, pos_acc, logsum, done_ct, out);
}